// Round 1
// baseline (325.331 us; speedup 1.0000x reference)
//
#include <hip/hip_runtime.h>

#define B_ 8
#define S_ 2048
#define M_ 256
#define D_ 512
#define P_ 512
#define H_ 8

#define SCALE 0.044194173824159216f  // 1/sqrt(512)

typedef __attribute__((ext_vector_type(8))) short bf16x8;
typedef __attribute__((ext_vector_type(4))) float f32x4;

static __device__ __forceinline__ float bf2f(short u) {
  union { float f; unsigned int i; } x;
  x.i = ((unsigned int)(unsigned short)u) << 16;
  return x.f;
}
static __device__ __forceinline__ short f2bf(float f) {
  union { float f; unsigned int i; } x;
  x.f = f;
  unsigned int r = (x.i + 0x7FFFu + ((x.i >> 16) & 1u)) >> 16;
  return (short)r;
}

// async global->LDS, 16B per lane; lds base must be wave-uniform
static __device__ __forceinline__ void gll16(const short* g, short* l) {
  __builtin_amdgcn_global_load_lds(
      (const __attribute__((address_space(1))) void*)g,
      (__attribute__((address_space(3))) void*)l, 16, 0, 0);
}

#define LGKM_WAIT() asm volatile("s_waitcnt lgkmcnt(0)" ::: "memory")
#define RAW_BAR() do { asm volatile("" ::: "memory"); __builtin_amdgcn_s_barrier(); asm volatile("" ::: "memory"); } while (0)

// ---------------------------------------------------------------------------
// fused fp32 -> bf16 cast (RNE) for input_seq and memory_cells
// ---------------------------------------------------------------------------
__global__ __launch_bounds__(256) void cast_both(
    const float* __restrict__ inA, short* __restrict__ outA, int n4A,
    const float* __restrict__ inM, short* __restrict__ outM)
{
  int idx = blockIdx.x * 256 + threadIdx.x;
  const float* in = inA;
  short* out = outA;
  if (idx >= n4A) { idx -= n4A; in = inM; out = outM; }
  float4 v = ((const float4*)in)[idx];
  short o0 = f2bf(v.x), o1 = f2bf(v.y), o2 = f2bf(v.z), o3 = f2bf(v.w);
  uint2 pk;
  pk.x = (unsigned int)(unsigned short)o0 | ((unsigned int)(unsigned short)o1 << 16);
  pk.y = (unsigned int)(unsigned short)o2 | ((unsigned int)(unsigned short)o3 << 16);
  ((uint2*)out)[idx] = pk;
}

// ---------------------------------------------------------------------------
// merged weight transpose+cast for the 512x512 weights:
// z==0: Wk->WkT, z==1: Wv->WvT, z>=2: Wq slice (z-2) -> WqT slice
// ---------------------------------------------------------------------------
__global__ __launch_bounds__(256) void wtrans_all(
    const float* __restrict__ Wk, const float* __restrict__ Wv,
    const float* __restrict__ Wq,
    short* __restrict__ WkT, short* __restrict__ WvT, short* __restrict__ WqT)
{
  __shared__ float tile[32][33];
  const int t = threadIdx.x, tx = t & 31, ty = t >> 5;
  const int z = blockIdx.z;
  const float* inp;
  short* outp;
  if (z == 0)      { inp = Wk; outp = WkT; }
  else if (z == 1) { inp = Wv; outp = WvT; }
  else             { inp = Wq + (size_t)(z - 2) * 512 * 512;
                     outp = WqT + (size_t)(z - 2) * 512 * 512; }
  const int n0 = blockIdx.x * 32, k0 = blockIdx.y * 32;
#pragma unroll
  for (int i = 0; i < 4; ++i)
    tile[ty + 8 * i][tx] = inp[(size_t)(k0 + ty + 8 * i) * 512 + n0 + tx];
  __syncthreads();
#pragma unroll
  for (int i = 0; i < 4; ++i)
    outp[(size_t)(n0 + ty + 8 * i) * 512 + k0 + tx] = f2bf(tile[tx][ty + 8 * i]);
}

// ---------------------------------------------------------------------------
// Wo transpose+cast: [4096 k][512 n] fp32 -> [512 n][4096 k] bf16
// ---------------------------------------------------------------------------
__global__ __launch_bounds__(256) void wtrans_wo(
    const float* __restrict__ in, short* __restrict__ out)
{
  __shared__ float tile[32][33];
  const int t = threadIdx.x, tx = t & 31, ty = t >> 5;
  const int n0 = blockIdx.x * 32, k0 = blockIdx.y * 32;
#pragma unroll
  for (int i = 0; i < 4; ++i)
    tile[ty + 8 * i][tx] = in[(size_t)(k0 + ty + 8 * i) * 512 + n0 + tx];
  __syncthreads();
#pragma unroll
  for (int i = 0; i < 4; ++i)
    out[(size_t)(n0 + ty + 8 * i) * 4096 + k0 + tx] = f2bf(tile[tx][ty + 8 * i]);
}

// ---------------------------------------------------------------------------
// 128x128 MFMA GEMM, BK=32, 2-barrier single-buffer K-loop. Still used for
// MODE 1 (q projection) and MODE 5 (Wo split-K). The two big GEMMs moved to
// gemm256 (8-phase schedule) below.
// ---------------------------------------------------------------------------
template<int MODE, int K, int N, int LDA, int LDB>
__global__ __launch_bounds__(256, 3) void gemm128(
    const short* __restrict__ Abase, const short* __restrict__ Bbase,
    const float* __restrict__ bias, void* __restrict__ Cv,
    const size_t aZ, const size_t bZ, const size_t cZ,
    float* __restrict__ Ls,
    const float* __restrict__ eselfp, const short* __restrict__ mvbp)
{
  __shared__ short As[4096];  // 128 rows x 32 k
  __shared__ short Bs[4096];
  const int t = threadIdx.x;
  const int w = t >> 6, lane = t & 63, qd = lane >> 4, ln = lane & 15;
  const int wm = (w & 1) * 64, wn = (w >> 1) * 64;

  int z, m0, n0, bsel;
  if constexpr (MODE == 2 || MODE == 3) {
    const int b = blockIdx.x;                 // XCD pin: flat id % 8 == b
    n0 = blockIdx.y * 128;
    const int h = blockIdx.z & 7, mb = blockIdx.z >> 3;
    z = b * 8 + h;
    m0 = mb * 128;
    bsel = b;
  } else {
    n0 = blockIdx.x * 128;
    m0 = blockIdx.y * 128;
    z = blockIdx.z;
    bsel = z;
  }

  const short* A  = Abase + (size_t)z * aZ;
  const short* Bp = Bbase + (size_t)bsel * bZ;

  const int rr = t >> 2, g0 = t & 3;
  const int gs0 = g0 ^ ((rr >> 1) & 3);
  const int gs1 = g0 ^ (((rr + 64) >> 1) & 3);
  const short* ga0 = A + (size_t)(m0 + rr) * LDA + gs0 * 8;
  const short* ga1 = A + (size_t)(m0 + rr + 64) * LDA + gs1 * 8;
  const short* gb0 = Bp + (size_t)(n0 + rr) * LDB + gs0 * 8;
  const short* gb1 = Bp + (size_t)(n0 + rr + 64) * LDB + gs1 * 8;

  int aoff[4], boff[4];
#pragma unroll
  for (int mt = 0; mt < 4; ++mt) {
    int r = wm + mt * 16 + ln;
    aoff[mt] = r * 32 + (qd ^ ((r >> 1) & 3)) * 8;
  }
#pragma unroll
  for (int nt = 0; nt < 4; ++nt) {
    int r = wn + nt * 16 + ln;
    boff[nt] = r * 32 + (qd ^ ((r >> 1) & 3)) * 8;
  }

  f32x4 acc[4][4];
#pragma unroll
  for (int mt = 0; mt < 4; ++mt)
#pragma unroll
    for (int nt = 0; nt < 4; ++nt) acc[mt][nt] = (f32x4){0.f, 0.f, 0.f, 0.f};

  for (int kc = 0; kc < K; kc += 32) {
    __syncthreads();
    gll16(ga0 + kc, &As[w * 512]);
    gll16(ga1 + kc, &As[2048 + w * 512]);
    gll16(gb0 + kc, &Bs[w * 512]);
    gll16(gb1 + kc, &Bs[2048 + w * 512]);
    __syncthreads();

    bf16x8 af[4], bfr[4];
#pragma unroll
    for (int mt = 0; mt < 4; ++mt) af[mt] = *(const bf16x8*)&As[aoff[mt]];
#pragma unroll
    for (int nt = 0; nt < 4; ++nt) bfr[nt] = *(const bf16x8*)&Bs[boff[nt]];
#pragma unroll
    for (int mt = 0; mt < 4; ++mt)
#pragma unroll
      for (int nt = 0; nt < 4; ++nt)
        acc[mt][nt] = __builtin_amdgcn_mfma_f32_16x16x32_bf16(af[mt], bfr[nt], acc[mt][nt], 0, 0, 0);
  }

  // ---- direct-store epilogues ----
  if constexpr (MODE == 5) {
#pragma unroll
    for (int nt = 0; nt < 4; ++nt) {
      const int col = n0 + wn + nt * 16 + ln;
#pragma unroll
      for (int mt = 0; mt < 4; ++mt)
#pragma unroll
        for (int r = 0; r < 4; ++r) {
          const int row = m0 + wm + mt * 16 + qd * 4 + r;
          ((float*)Cv)[(size_t)z * cZ + (size_t)row * N + col] = acc[mt][nt][r];
        }
    }
  } else if constexpr (MODE == 2) {
#pragma unroll
    for (int mt = 0; mt < 4; ++mt)
#pragma unroll
      for (int nt = 0; nt < 4; ++nt)
#pragma unroll
        for (int r = 0; r < 4; ++r)
          acc[mt][nt][r] = __expf(acc[mt][nt][r] * SCALE);
#pragma unroll
    for (int mt = 0; mt < 4; ++mt)
#pragma unroll
      for (int r = 0; r < 4; ++r) {
        float rsum = acc[mt][0][r] + acc[mt][1][r] + acc[mt][2][r] + acc[mt][3][r];
        rsum += __shfl_xor(rsum, 1);
        rsum += __shfl_xor(rsum, 2);
        rsum += __shfl_xor(rsum, 4);
        rsum += __shfl_xor(rsum, 8);
        if (ln == 0) {
          const int row = m0 + wm + mt * 16 + qd * 4 + r;
          atomicAdd(&Ls[(size_t)z * M_ + row], rsum);
        }
      }
#pragma unroll
    for (int nt = 0; nt < 4; ++nt) {
      const int col = n0 + wn + nt * 16 + ln;
#pragma unroll
      for (int mt = 0; mt < 4; ++mt)
#pragma unroll
        for (int r = 0; r < 4; ++r) {
          const int row = m0 + wm + mt * 16 + qd * 4 + r;
          ((short*)Cv)[(size_t)z * cZ + (size_t)row * N + col] = f2bf(acc[mt][nt][r]);
        }
    }
  } else if constexpr (MODE == 3) {
    const int zb = z >> 3, hh = z & 7;
#pragma unroll
    for (int mt = 0; mt < 4; ++mt)
#pragma unroll
      for (int r = 0; r < 4; ++r) {
        const int row = m0 + wm + mt * 16 + qd * 4 + r;
        const float es = eselfp[(size_t)z * M_ + row];
        const float inv = 1.f / (es + Ls[(size_t)z * M_ + row]);
        const short* mvr = mvbp + ((size_t)(zb * M_ + row)) * P_;
        short* outr = (short*)Cv + ((size_t)(zb * M_ + row)) * (H_ * P_) + (size_t)hh * P_;
#pragma unroll
        for (int nt = 0; nt < 4; ++nt) {
          const int col = n0 + wn + nt * 16 + ln;
          outr[col] = f2bf((acc[mt][nt][r] + es * bf2f(mvr[col])) * inv);
        }
      }
  } else {  // MODE 1
#pragma unroll
    for (int nt = 0; nt < 4; ++nt) {
      const int col = n0 + wn + nt * 16 + ln;
      const float bc = bias[512 * z + col];
#pragma unroll
      for (int mt = 0; mt < 4; ++mt)
#pragma unroll
        for (int r = 0; r < 4; ++r) {
          const int row = m0 + wm + mt * 16 + qd * 4 + r;
          const int bidx = row >> 8, ml = row & 255;
          ((short*)Cv)[((size_t)(bidx * H_ + z) * M_ + ml) * N + col] = f2bf(acc[mt][nt][r] + bc);
        }
    }
  }
}

// ---------------------------------------------------------------------------
// 16 MFMAs of one 64x32 C-quadrant over K=64 (kk=0,1), setprio-wrapped (T5).
// ---------------------------------------------------------------------------
template<int MH, int NH>
static __device__ __forceinline__ void mfma_quad(
    f32x4 (&acc)[8][4], const bf16x8 (&a)[4][2], const bf16x8 (&bfr)[2][2])
{
  __builtin_amdgcn_s_setprio(1);
#pragma unroll
  for (int kk = 0; kk < 2; ++kk)
#pragma unroll
    for (int mt = 0; mt < 4; ++mt)
#pragma unroll
      for (int nt = 0; nt < 2; ++nt)
        acc[MH * 4 + mt][NH * 2 + nt] = __builtin_amdgcn_mfma_f32_16x16x32_bf16(
            a[mt][kk], bfr[nt][kk], acc[MH * 4 + mt][NH * 2 + nt], 0, 0, 0);
  __builtin_amdgcn_s_setprio(0);
}

// ---------------------------------------------------------------------------
// 256x256 8-phase MFMA GEMM, BK=64, 512 threads (8 waves 2Mx4N), 128 KiB
// double-buffered LDS. Per-batch A [2048][LDA], B [N][LDB] (B^T layout),
// grid (8 batches = XCD-pinned, N/256, M/256).
//
// Schedule (tile t, buf p=t&1; raw s_barrier, counted vmcnt -- T3+T4):
//   ph0: ds_read A-mh0 (8xb128) + B-nh0 (4) | stage A0(t+1),B1(t+1)->buf p^1
//   ph1: ds_read A-mh1 (8)                  | stage A1(t+1)->buf p^1
//   ph2: ds_read B-nh1 (4)                  | (no stage)
//   ph3: ds_read A-mh0 again (8)            | stage B0(t+2)->buf p
//        ... MFMA ... s_waitcnt vmcnt(2) ... barrier   <- tile boundary
// Each phase: reads/stage -> barrier -> lgkmcnt(0) -> 16 MFMA -> barrier.
// Race-freedom: region R of buf q is staged only in a phase strictly after
// R's last ds_read of the previous K-tile occupying buf q (A region free
// after ph3 via its end-barrier; B region free after ph2). Boundary vmcnt(2)
// leaves only B0(t+2) in flight (issued ph3) -- never drains to 0 mid-loop.
//
// LDS swizzle (T2): 16B-chunk index c of row r stored at c^(r&7). Involution,
// 16B-granular, so it composes with global_load_lds by pre-swizzling the
// per-lane GLOBAL source (LDS dest stays linear, guide rule 21). Fragment
// ds_read_b128 (lanes (ln,qd) -> slot (row)*8 + (kk*4+qd)^(ln&7)) then hits
// each of the 8 bank-groups exactly 8 times -> conflict-free. Global reads
// stay full-row coalesced (8 lanes permute chunks within one 128B row).
//
// MODE 2: C = exp(acc*SCALE) bf16 [2048][2048]/batch + rowsum atomics to Ls
// MODE 3: C = (acc + eself*mv)/(eself+Ls) concat scatter to valb
// ---------------------------------------------------------------------------
template<int MODE, int K, int LDA, int LDB>
__global__ __launch_bounds__(512, 2) void gemm256(
    const short* __restrict__ Abase, const short* __restrict__ Bbase,
    void* __restrict__ Cv, float* __restrict__ Ls,
    const float* __restrict__ eselfp, const short* __restrict__ mvbp,
    const size_t aZ, const size_t bZ)
{
  __shared__ short lds[65536];   // A: 2buf x 2half x [128][64] | B: same, +32768
  constexpr int NKT = K / 64;
  static_assert(NKT >= 2, "need at least 2 K-tiles");
  const int t = threadIdx.x;
  const int w = t >> 6, lane = t & 63, qd = lane >> 4, ln = lane & 15;
  const int wr = w >> 2, wc = w & 3;
  const int b = blockIdx.x;                       // XCD pin: flat id % 8 == b
  const int n0 = blockIdx.y * 256, m0 = blockIdx.z * 256;

  const short* A  = Abase + (size_t)b * aZ;
  const short* Bp = Bbase + (size_t)b * bZ;

  // staging source map: linear LDS slot s gets global (row=s>>3, chunk=(s&7)^(row&7))
  const int s0 = w * 64 + lane, s1 = s0 + 512;
  const int sr0 = s0 >> 3, sc0 = ((s0 & 7) ^ (sr0 & 7)) * 8;
  const int sr1 = s1 >> 3, sc1 = ((s1 & 7) ^ (sr1 & 7)) * 8;

  auto stage = [&](const short* gorigin, int ldg, short* lbase) {
    gll16(gorigin + (size_t)sr0 * ldg + sc0, lbase + w * 512);
    gll16(gorigin + (size_t)sr1 * ldg + sc1, lbase + 4096 + w * 512);
  };

  // fragment read chunk offsets (shorts): chunk (kk*4+qd) ^ (ln&7)
  const int cq0 = ((qd    ) ^ (ln & 7)) * 8;
  const int cq1 = ((4 + qd) ^ (ln & 7)) * 8;
  const int brow = (wc & 1) * 64;

  f32x4 acc[8][4];
#pragma unroll
  for (int i = 0; i < 8; ++i)
#pragma unroll
    for (int j = 0; j < 4; ++j) acc[i][j] = (f32x4){0.f, 0.f, 0.f, 0.f};

  // ---- prologue: tile0 (all 4 half-tiles) + B0(1); drain tile0, keep B0(1) in flight
  stage(A  + (size_t)m0 * LDA,          LDA, &lds[0]);              // A0(0)
  stage(A  + (size_t)(m0 + 128) * LDA,  LDA, &lds[8192]);           // A1(0)
  stage(Bp + (size_t)n0 * LDB,          LDB, &lds[32768]);          // B0(0)
  stage(Bp + (size_t)(n0 + 128) * LDB,  LDB, &lds[32768 + 8192]);   // B1(0)
  stage(Bp + (size_t)n0 * LDB + 64,     LDB, &lds[32768 + 16384]);  // B0(1) -> buf1
  asm volatile("s_waitcnt vmcnt(2)" ::: "memory");
  __builtin_amdgcn_s_barrier();

#pragma unroll 1
  for (int kt = 0; kt < NKT; ++kt) {
    const int p = kt & 1;
    short* Ah = &lds[p * 16384 + wr * 8192];
    short* Bh = &lds[32768 + p * 16384 + (wc >> 1) * 8192];
    bf16x8 a[4][2], bfr[2][2];

    // ---- phase 0: A mh0 + B nh0; stage A0(kt+1), B1(kt+1) -> buf p^1
#pragma unroll
    for (int mt = 0; mt < 4; ++mt) {
      a[mt][0] = *(const bf16x8*)&Ah[(mt * 16 + ln) * 64 + cq0];
      a[mt][1] = *(const bf16x8*)&Ah[(mt * 16 + ln) * 64 + cq1];
    }
#pragma unroll
    for (int nt = 0; nt < 2; ++nt) {
      bfr[nt][0] = *(const bf16x8*)&Bh[(brow + nt * 16 + ln) * 64 + cq0];
      bfr[nt][1] = *(const bf16x8*)&Bh[(brow + nt * 16 + ln) * 64 + cq1];
    }
    if (kt + 1 < NKT) {
      stage(A  + (size_t)m0 * LDA + (kt + 1) * 64,          LDA, &lds[(p ^ 1) * 16384]);
      stage(Bp + (size_t)(n0 + 128) * LDB + (kt + 1) * 64,  LDB, &lds[32768 + (p ^ 1) * 16384 + 8192]);
    }
    RAW_BAR(); LGKM_WAIT();
    mfma_quad<0, 0>(acc, a, bfr);
    RAW_BAR();

    // ---- phase 1: A mh1; stage A1(kt+1) -> buf p^1
#pragma unroll
    for (int mt = 0; mt < 4; ++mt) {
      a[mt][0] = *(const bf16x8*)&Ah[4096 + (mt * 16 + ln) * 64 + cq0];
      a[mt][1] = *(const bf16x8*)&Ah[4096 + (mt * 16 + ln) * 64 + cq1];
    }
    if (kt + 1 < NKT)
      stage(A + (size_t)(m0 + 128) * LDA + (kt + 1) * 64, LDA, &lds[(p ^ 1) * 16384 + 8192]);
    RAW_BAR(); LGKM_WAIT();
    mfma_quad<1, 0>(acc, a, bfr);
    RAW_BAR();

    // ---- phase 2: B nh1 (no stage)
#pragma unroll
    for (int nt = 0; nt < 2; ++nt) {
      bfr[nt][0] = *(const bf16x8*)&Bh[(brow + 32 + nt * 16 + ln) * 64 + cq0];
      bfr[nt][1] = *(const bf16x8*)&Bh[(brow + 32 + nt * 16 + ln) * 64 + cq1];
    }
    RAW_BAR(); LGKM_WAIT();
    mfma_quad<1, 1>(acc, a, bfr);
    RAW_BAR();

    // ---- phase 3: A mh0 again; stage B0(kt+2) -> buf p; boundary vmcnt
#pragma unroll
    for (int mt = 0; mt < 4; ++mt) {
      a[mt][0] = *(const bf16x8*)&Ah[(mt * 16 + ln) * 64 + cq0];
      a[mt][1] = *(const bf16x8*)&Ah[(mt * 16 + ln) * 64 + cq1];
    }
    if (kt + 2 < NKT)
      stage(Bp + (size_t)n0 * LDB + (kt + 2) * 64, LDB, &lds[32768 + p * 16384]);
    RAW_BAR(); LGKM_WAIT();
    mfma_quad<0, 1>(acc, a, bfr);
    if (kt + 2 < NKT) { asm volatile("s_waitcnt vmcnt(2)" ::: "memory"); }
    else              { asm volatile("s_waitcnt vmcnt(0)" ::: "memory"); }
    RAW_BAR();
  }

  // ---- epilogues ----
  if constexpr (MODE == 2) {
#pragma unroll
    for (int i = 0; i < 8; ++i)
#pragma unroll
      for (int j = 0; j < 4; ++j)
#pragma unroll
        for (int r = 0; r < 4; ++r)
          acc[i][j][r] = __expf(acc[i][j][r] * SCALE);
#pragma unroll
    for (int i = 0; i < 8; ++i)
#pragma unroll
      for (int r = 0; r < 4; ++r) {
        float rs = acc[i][0][r] + acc[i][1][r] + acc[i][2][r] + acc[i][3][r];
        rs += __shfl_xor(rs, 1);
        rs += __shfl_xor(rs, 2);
        rs += __shfl_xor(rs, 4);
        rs += __shfl_xor(rs, 8);
        if (ln == 0) {
          const int row = m0 + wr * 128 + i * 16 + qd * 4 + r;
          atomicAdd(&Ls[(size_t)b * 2048 + row], rs);
        }
      }
    short* Cb = (short*)Cv + (size_t)b * 2048 * 2048;
#pragma unroll
    for (int j = 0; j < 4; ++j) {
      const int col = n0 + wc * 64 + j * 16 + ln;
#pragma unroll
      for (int i = 0; i < 8; ++i)
#pragma unroll
        for (int r = 0; r < 4; ++r) {
          const int row = m0 + wr * 128 + i * 16 + qd * 4 + r;
          Cb[(size_t)row * 2048 + col] = f2bf(acc[i][j][r]);
        }
    }
  } else {  // MODE 3
#pragma unroll
    for (int i = 0; i < 8; ++i)
#pragma unroll
      for (int r = 0; r < 4; ++r) {
        const int R = m0 + wr * 128 + i * 16 + qd * 4 + r;   // h*256+m
        const float es  = eselfp[(size_t)b * 2048 + R];
        const float inv = 1.f / (es + Ls[(size_t)b * 2048 + R]);
        const int h = R >> 8, m = R & 255;
        const short* mvr = mvbp + ((size_t)(b * 256 + m)) * 512;
        short* outr = (short*)Cv + ((size_t)(b * 256 + m)) * 4096 + (size_t)h * 512;
#pragma unroll
        for (int j = 0; j < 4; ++j) {
          const int col = n0 + wc * 64 + j * 16 + ln;
          outr[col] = f2bf((acc[i][j][r] + es * bf2f(mvr[col])) * inv);
        }
      }
  }
}

// ---------------------------------------------------------------------------
// merged K/V projection, BK=32, 2-barrier single-buffer (16 KB LDS).
// Ck = A@WkT + bk row-major direct. TRANSV=true: V written transposed into
// ivT (B,P,S) via LDS transpose reusing the staging buffer.
// ---------------------------------------------------------------------------
template<bool TRANSV>
__global__ __launch_bounds__(256, 3) void proj_kv(
    const short* __restrict__ A,
    const short* __restrict__ WkT, const short* __restrict__ WvT,
    const float* __restrict__ bk, const float* __restrict__ bv,
    short* __restrict__ Ck, short* __restrict__ Cvv)
{
  __shared__ short Sh[8192];   // As 128x32 | Bks 64x32 | Bvs 64x32
  short* As  = Sh;             // 4096 shorts
  short* Bks = Sh + 4096;      // 2048
  short* Bvs = Sh + 6144;      // 2048
  const int t = threadIdx.x;
  const int w = t >> 6, lane = t & 63, qd = lane >> 4, ln = lane & 15;
  const int n0 = blockIdx.x * 64, m0 = blockIdx.y * 128;
  const int wm = (w & 1) * 64, wn2 = (w >> 1) * 32;

  const int rr = t >> 2, g0 = t & 3;
  const int gs0 = g0 ^ ((rr >> 1) & 3);
  const int gs1 = g0 ^ (((rr + 64) >> 1) & 3);
  const short* ga0 = A + (size_t)(m0 + rr) * 512 + gs0 * 8;
  const short* ga1 = A + (size_t)(m0 + rr + 64) * 512 + gs1 * 8;
  const short* gbk = WkT + (size_t)(n0 + rr) * 512 + gs0 * 8;
  const short* gbv = WvT + (size_t)(n0 + rr) * 512 + gs0 * 8;

  int aoff[4], boff[2];
#pragma unroll
  for (int mt = 0; mt < 4; ++mt) {
    int r = wm + mt * 16 + ln;
    aoff[mt] = r * 32 + (qd ^ ((r >> 1) & 3)) * 8;
  }
#pragma unroll
  for (int nt = 0; nt < 2; ++nt) {
    int r = wn2 + nt * 16 + ln;
    boff[nt] = r * 32 + (qd ^ ((r >> 1) & 3)) * 8;
  }

  f32x4 accK[4][2], accV[4][2];
#pragma unroll
  for (int mt = 0; mt < 4; ++mt)
#pragma unroll
    for (int nt = 0; nt < 2; ++nt) {
      accK[mt][nt] = (f32x4){0.f, 0.f, 0.f, 0.f};
      accV[mt][nt] = (f32x4){0.f, 0.f, 0.f, 0.f};
    }

  for (int kc = 0; kc < 512; kc += 32) {
    __syncthreads();
    gll16(ga0 + kc, &As[w * 512]);
    gll16(ga1 + kc, &As[2048 + w * 512]);
    gll16(gbk + kc, &Bks[w * 512]);
    gll16(gbv + kc, &Bvs[w * 512]);
    __syncthreads();

    bf16x8 af[4], bkf[2], bvf[2];
#pragma unroll
    for (int mt = 0; mt < 4; ++mt) af[mt] = *(const bf16x8*)&As[aoff[mt]];
#pragma unroll
    for (int nt = 0; nt < 2; ++nt) {
      bkf[nt] = *(const bf16x8*)&Bks[boff[nt]];
      bvf[nt] = *(const bf16x8*)&Bvs[boff[nt]];
    }
#pragma unroll
    for (int mt = 0; mt < 4; ++mt)
#pragma unroll
      for (int nt = 0; nt < 2; ++nt) {
        accK[mt][nt] = __builtin_amdgcn_mfma_f32_16x16x32_bf16(af[mt], bkf[nt], accK[mt][nt], 0, 0, 0);
        accV[mt][nt] = __builtin_amdgcn_mfma_f32_16x16x32_bf16(af[mt], bvf[nt], accV[mt][nt], 0, 0, 0);
      }
  }

  // ---- K epilogue: direct scattered stores
#pragma unroll
  for (int nt = 0; nt < 2; ++nt) {
    const int col = n0 + wn2 + nt * 16 + ln;
    const float bc = bk[col];
#pragma unroll
    for (int mt = 0; mt < 4; ++mt)
#pragma unroll
      for (int r = 0; r < 4; ++r) {
        const int row = m0 + wm + mt * 16 + qd * 4 + r;
        Ck[(size_t)row * 512 + col] = f2bf(accK[mt][nt][r] + bc);
      }
  }

  // ---- V epilogue
  if constexpr (!TRANSV) {
#pragma unroll
    for (int nt = 0; nt < 2; ++nt) {
      const int col = n0 + wn2 + nt * 16 + ln;
      const float bc = bv[col];
#pragma unroll
      for (int mt = 0; mt < 4; ++mt)
#pragma unroll
        for (int r = 0; r < 4; ++r) {
          const int row = m0 + wm + mt * 16 + qd * 4 + r;
          Cvv[(size_t)row * 512 + col] = f2bf(accV[mt][nt][r] + bc);
        }
    }
  } else {
    // transpose via LDS reuse (staging dead). per-wave 32x40 tile.
    __syncthreads();
    short* ep = &Sh[w * 1280];
    const int lr = lane >> 1, lc16 = (lane & 1) * 16;
#pragma unroll
    for (int pass = 0; pass < 2; ++pass) {
#pragma unroll
      for (int mh = 0; mh < 2; ++mh) {
        const int mt = pass * 2 + mh;
#pragma unroll
        for (int nt = 0; nt < 2; ++nt) {
          const float bc = bv[n0 + wn2 + nt * 16 + ln];
#pragma unroll
          for (int r = 0; r < 4; ++r)
            ep[(nt * 16 + ln) * 40 + mh * 16 + qd * 4 + r] = f2bf(accV[mt][nt][r] + bc);
        }
      }
      LGKM_WAIT();
      const int srow0 = m0 + wm + pass * 32;
      const int bidx = srow0 >> 11;
      const int sloc = (srow0 & 2047) + lc16;
      const int pcol = n0 + wn2 + lr;
      short* outp = Cvv + (size_t)bidx * P_ * S_ + (size_t)pcol * S_ + sloc;
      *(bf16x8*)outp = *(const bf16x8*)&ep[lr * 40 + lc16];
      *(bf16x8*)(outp + 8) = *(const bf16x8*)&ep[lr * 40 + lc16 + 8];
      LGKM_WAIT();
    }
  }
}

// ---------------------------------------------------------------------------
// split-K reduce for Wo: out = sum_z partial[z] + bo[col], fp32
// ---------------------------------------------------------------------------
__global__ __launch_bounds__(256) void reduce_wo(
    const float* __restrict__ partial, const float* __restrict__ bo,
    float* __restrict__ out)
{
  const int idx4 = blockIdx.x * 256 + threadIdx.x;   // float4 index, 262144
  float4 s = ((const float4*)bo)[idx4 & 127];
#pragma unroll
  for (int zz = 0; zz < 4; ++zz) {
    float4 p = ((const float4*)partial)[(size_t)zz * 262144 + idx4];
    s.x += p.x; s.y += p.y; s.z += p.z; s.w += p.w;
  }
  ((float4*)out)[idx4] = s;
}

// ---------------------------------------------------------------------------
// self-score + Ls zeroing (runs BEFORE the QK kernel that atomicAdds Ls):
// eself[z*256+m] = exp(scale * q[z][m][:] . mk[b][m][:]);  Ls[z*256+m] = 0
// ---------------------------------------------------------------------------
__global__ __launch_bounds__(256) void selfscore(
    const short* __restrict__ qb, const short* __restrict__ mkb,
    float* __restrict__ eself, float* __restrict__ Ls)
{
  const int z = blockIdx.x, t = threadIdx.x;
  const short* qr = qb + ((size_t)z * M_ + t) * P_;
  const short* mr = mkb + ((size_t)(z >> 3) * M_ + t) * P_;
  float s = 0.f;
#pragma unroll 8
  for (int c = 0; c < P_; c += 8) {
    bf16x8 qv = *(const bf16x8*)(qr + c);
    bf16x8 mv = *(const bf16x8*)(mr + c);
#pragma unroll
    for (int j = 0; j < 8; ++j) s += bf2f(qv[j]) * bf2f(mv[j]);
  }
  eself[(size_t)z * M_ + t] = __expf(s * SCALE);
  Ls[(size_t)z * M_ + t] = 0.f;
}

// ---------------------------------------------------------------------------
extern "C" void kernel_launch(void* const* d_in, const int* in_sizes, int n_in,
                              void* d_out, int out_size, void* d_ws, size_t ws_size,
                              hipStream_t stream) {
  const float* input_seq = (const float*)d_in[0];
  const float* memcells  = (const float*)d_in[1];
  const float* Wk = (const float*)d_in[2];
  const float* bk = (const float*)d_in[3];
  const float* Wv = (const float*)d_in[4];
  const float* bv = (const float*)d_in[5];
  const float* Wq = (const float*)d_in[6];
  const float* bq = (const float*)d_in[7];
  const float* Wo = (const float*)d_in[8];
  const float* bo = (const float*)d_in[9];
  float* out = (float*)d_out;

  // ---- workspace carve (shorts). region2 time-shared: {Ab,Mb,W*T} dead
  // before Eb written. 'partial' region reused for Wo split-K fp32 partials.
  short* ws = (short*)d_ws;
  size_t o = 0;
  short* valb = ws + o; o += (size_t)B_ * M_ * H_ * P_;      // 8388608
  short* WoT  = ws + o; o += (size_t)(H_ * P_) * P_;          // 2097152
  short* mvb  = ws + o; o += (size_t)B_ * M_ * P_;            // 1048576
  short* mkb  = ws + o; o += (size_t)B_ * M_ * P_;            // 1048576
  short* qb   = ws + o; o += (size_t)B_ * H_ * M_ * P_;       // 8388608
  short* ivT  = ws + o; o += (size_t)B_ * P_ * S_;            // 8388608
  short* ikb  = ws + o; o += (size_t)B_ * S_ * P_;            // 8388608
  float* partial = (float*)(ws + o); o += (size_t)B_ * H_ * M_ * P_;  // 16 MB
  float* eself = (float*)(ws + o); o += 2 * (size_t)B_ * H_ * M_;
  float* Ls    = (float*)(ws + o); o += 2 * (size_t)B_ * H_ * M_;
  short* region2 = ws + o;                                    // Eb region (64 MB)
  short* Ab  = region2;
  short* Mb  = Ab + (size_t)B_ * S_ * D_;
  short* WkT = Mb + (size_t)B_ * M_ * D_;
  short* WvT = WkT + (size_t)D_ * P_;
  short* WqT = WvT + (size_t)D_ * P_;
  short* Eb  = region2;   // overlaps the above (all dead before E is written)

  dim3 blk(256);

  // casts + weight transposes
  const int n4A = B_ * S_ * D_ / 4;
  const int n4M = B_ * M_ * D_ / 4;
  cast_both<<<dim3((n4A + n4M) / 256), blk, 0, stream>>>(input_seq, Ab, n4A, memcells, Mb);
  wtrans_all<<<dim3(16, 16, 10), blk, 0, stream>>>(Wk, Wv, Wq, WkT, WvT, WqT);
  wtrans_wo<<<dim3(16, 128), blk, 0, stream>>>(Wo, WoT);

  // merged K/V projections; big one emits ivT directly (transposed V)
  proj_kv<true><<<dim3(8, 128), blk, 0, stream>>>(Ab, WkT, WvT, bk, bv, ikb, ivT);
  proj_kv<false><<<dim3(8, 16), blk, 0, stream>>>(Mb, WkT, WvT, bk, bv, mkb, mvb);

  // q projection: MODE 1, z = h
  gemm128<1, 512, 512, 512, 512><<<dim3(4, 16, 8), blk, 0, stream>>>(
      Mb, WqT, bq, qb, 0, (size_t)D_ * P_, 0, nullptr, nullptr, nullptr);

  // eself + zero Ls (before QK's atomics)
  selfscore<<<dim3(64), blk, 0, stream>>>(qb, mkb, eself, Ls);

  // E = exp(scale * q @ ik^T) + fused row-sum; per-batch 2048x2048, K=512
  gemm256<2, 512, 512, 512><<<dim3(8, 8, 8), dim3(512), 0, stream>>>(
      qb, ikb, Eb, Ls, nullptr, nullptr,
      (size_t)2048 * 512, (size_t)2048 * 512);

  // val = normalize(E @ iv + eself*mv) fused, concat layout; per-batch
  // 2048x512, K=2048 (128 blocks -- known CU under-fill, next lever)
  gemm256<3, 2048, 2048, 2048><<<dim3(8, 2, 8), dim3(512), 0, stream>>>(
      Eb, ivT, valb, Ls, eself, mvb,
      (size_t)2048 * 2048, (size_t)512 * 2048);

  // Wo: split-K=4 partials (grid 256 blocks), then reduce+bias
  gemm128<5, 1024, 512, 4096, 4096><<<dim3(4, 16, 4), blk, 0, stream>>>(
      valb, WoT, nullptr, partial, 1024, 1024,
      (size_t)2048 * 512, nullptr, nullptr, nullptr);
  reduce_wo<<<dim3(1024), blk, 0, stream>>>(partial, bo, out);
}

// Round 2
// 305.070 us; speedup vs baseline: 1.0664x; 1.0664x over previous
//
#include <hip/hip_runtime.h>

#define B_ 8
#define S_ 2048
#define M_ 256
#define D_ 512
#define P_ 512
#define H_ 8

#define SCALE 0.044194173824159216f  // 1/sqrt(512)

typedef __attribute__((ext_vector_type(8))) short bf16x8;
typedef __attribute__((ext_vector_type(4))) float f32x4;

static __device__ __forceinline__ float bf2f(short u) {
  union { float f; unsigned int i; } x;
  x.i = ((unsigned int)(unsigned short)u) << 16;
  return x.f;
}
static __device__ __forceinline__ short f2bf(float f) {
  union { float f; unsigned int i; } x;
  x.f = f;
  unsigned int r = (x.i + 0x7FFFu + ((x.i >> 16) & 1u)) >> 16;
  return (short)r;
}

// async global->LDS, 16B per lane; lds base must be wave-uniform
static __device__ __forceinline__ void gll16(const short* g, short* l) {
  __builtin_amdgcn_global_load_lds(
      (const __attribute__((address_space(1))) void*)g,
      (__attribute__((address_space(3))) void*)l, 16, 0, 0);
}

#define LGKM_WAIT() asm volatile("s_waitcnt lgkmcnt(0)" ::: "memory")
// rule #18: sched_barrier(0) right after lgkm wait so MFMA can't hoist past it
#define LGKM_SYNC() do { asm volatile("s_waitcnt lgkmcnt(0)" ::: "memory"); \
                         __builtin_amdgcn_sched_barrier(0); } while (0)
#define RAW_BAR() do { asm volatile("" ::: "memory"); __builtin_amdgcn_s_barrier(); asm volatile("" ::: "memory"); } while (0)

// ---------------------------------------------------------------------------
// fused fp32 -> bf16 cast (RNE) for input_seq and memory_cells
// ---------------------------------------------------------------------------
__global__ __launch_bounds__(256) void cast_both(
    const float* __restrict__ inA, short* __restrict__ outA, int n4A,
    const float* __restrict__ inM, short* __restrict__ outM)
{
  int idx = blockIdx.x * 256 + threadIdx.x;
  const float* in = inA;
  short* out = outA;
  if (idx >= n4A) { idx -= n4A; in = inM; out = outM; }
  float4 v = ((const float4*)in)[idx];
  short o0 = f2bf(v.x), o1 = f2bf(v.y), o2 = f2bf(v.z), o3 = f2bf(v.w);
  uint2 pk;
  pk.x = (unsigned int)(unsigned short)o0 | ((unsigned int)(unsigned short)o1 << 16);
  pk.y = (unsigned int)(unsigned short)o2 | ((unsigned int)(unsigned short)o3 << 16);
  ((uint2*)out)[idx] = pk;
}

// ---------------------------------------------------------------------------
// merged weight transpose+cast for the 512x512 weights
// ---------------------------------------------------------------------------
__global__ __launch_bounds__(256) void wtrans_all(
    const float* __restrict__ Wk, const float* __restrict__ Wv,
    const float* __restrict__ Wq,
    short* __restrict__ WkT, short* __restrict__ WvT, short* __restrict__ WqT)
{
  __shared__ float tile[32][33];
  const int t = threadIdx.x, tx = t & 31, ty = t >> 5;
  const int z = blockIdx.z;
  const float* inp;
  short* outp;
  if (z == 0)      { inp = Wk; outp = WkT; }
  else if (z == 1) { inp = Wv; outp = WvT; }
  else             { inp = Wq + (size_t)(z - 2) * 512 * 512;
                     outp = WqT + (size_t)(z - 2) * 512 * 512; }
  const int n0 = blockIdx.x * 32, k0 = blockIdx.y * 32;
#pragma unroll
  for (int i = 0; i < 4; ++i)
    tile[ty + 8 * i][tx] = inp[(size_t)(k0 + ty + 8 * i) * 512 + n0 + tx];
  __syncthreads();
#pragma unroll
  for (int i = 0; i < 4; ++i)
    outp[(size_t)(n0 + ty + 8 * i) * 512 + k0 + tx] = f2bf(tile[tx][ty + 8 * i]);
}

// ---------------------------------------------------------------------------
// Wo transpose+cast: [4096 k][512 n] fp32 -> [512 n][4096 k] bf16
// ---------------------------------------------------------------------------
__global__ __launch_bounds__(256) void wtrans_wo(
    const float* __restrict__ in, short* __restrict__ out)
{
  __shared__ float tile[32][33];
  const int t = threadIdx.x, tx = t & 31, ty = t >> 5;
  const int n0 = blockIdx.x * 32, k0 = blockIdx.y * 32;
#pragma unroll
  for (int i = 0; i < 4; ++i)
    tile[ty + 8 * i][tx] = in[(size_t)(k0 + ty + 8 * i) * 512 + n0 + tx];
  __syncthreads();
#pragma unroll
  for (int i = 0; i < 4; ++i)
    out[(size_t)(n0 + ty + 8 * i) * 4096 + k0 + tx] = f2bf(tile[tx][ty + 8 * i]);
}

// ---------------------------------------------------------------------------
// 128x128 MFMA GEMM, BK=32, 2-barrier single-buffer K-loop. Used for
// MODE 1 (q projection) and MODE 5 (Wo split-K).
// ---------------------------------------------------------------------------
template<int MODE, int K, int N, int LDA, int LDB>
__global__ __launch_bounds__(256, 3) void gemm128(
    const short* __restrict__ Abase, const short* __restrict__ Bbase,
    const float* __restrict__ bias, void* __restrict__ Cv,
    const size_t aZ, const size_t bZ, const size_t cZ,
    float* __restrict__ Ls,
    const float* __restrict__ eselfp, const short* __restrict__ mvbp)
{
  __shared__ short As[4096];
  __shared__ short Bs[4096];
  const int t = threadIdx.x;
  const int w = t >> 6, lane = t & 63, qd = lane >> 4, ln = lane & 15;
  const int wm = (w & 1) * 64, wn = (w >> 1) * 64;

  const int n0 = blockIdx.x * 128;
  const int m0 = blockIdx.y * 128;
  const int z = blockIdx.z;
  const int bsel = z;

  const short* A  = Abase + (size_t)z * aZ;
  const short* Bp = Bbase + (size_t)bsel * bZ;

  const int rr = t >> 2, g0 = t & 3;
  const int gs0 = g0 ^ ((rr >> 1) & 3);
  const int gs1 = g0 ^ (((rr + 64) >> 1) & 3);
  const short* ga0 = A + (size_t)(m0 + rr) * LDA + gs0 * 8;
  const short* ga1 = A + (size_t)(m0 + rr + 64) * LDA + gs1 * 8;
  const short* gb0 = Bp + (size_t)(n0 + rr) * LDB + gs0 * 8;
  const short* gb1 = Bp + (size_t)(n0 + rr + 64) * LDB + gs1 * 8;

  int aoff[4], boff[4];
#pragma unroll
  for (int mt = 0; mt < 4; ++mt) {
    int r = wm + mt * 16 + ln;
    aoff[mt] = r * 32 + (qd ^ ((r >> 1) & 3)) * 8;
  }
#pragma unroll
  for (int nt = 0; nt < 4; ++nt) {
    int r = wn + nt * 16 + ln;
    boff[nt] = r * 32 + (qd ^ ((r >> 1) & 3)) * 8;
  }

  f32x4 acc[4][4];
#pragma unroll
  for (int mt = 0; mt < 4; ++mt)
#pragma unroll
    for (int nt = 0; nt < 4; ++nt) acc[mt][nt] = (f32x4){0.f, 0.f, 0.f, 0.f};

  for (int kc = 0; kc < K; kc += 32) {
    __syncthreads();
    gll16(ga0 + kc, &As[w * 512]);
    gll16(ga1 + kc, &As[2048 + w * 512]);
    gll16(gb0 + kc, &Bs[w * 512]);
    gll16(gb1 + kc, &Bs[2048 + w * 512]);
    __syncthreads();

    bf16x8 af[4], bfr[4];
#pragma unroll
    for (int mt = 0; mt < 4; ++mt) af[mt] = *(const bf16x8*)&As[aoff[mt]];
#pragma unroll
    for (int nt = 0; nt < 4; ++nt) bfr[nt] = *(const bf16x8*)&Bs[boff[nt]];
#pragma unroll
    for (int mt = 0; mt < 4; ++mt)
#pragma unroll
      for (int nt = 0; nt < 4; ++nt)
        acc[mt][nt] = __builtin_amdgcn_mfma_f32_16x16x32_bf16(af[mt], bfr[nt], acc[mt][nt], 0, 0, 0);
  }

  if constexpr (MODE == 5) {
#pragma unroll
    for (int nt = 0; nt < 4; ++nt) {
      const int col = n0 + wn + nt * 16 + ln;
#pragma unroll
      for (int mt = 0; mt < 4; ++mt)
#pragma unroll
        for (int r = 0; r < 4; ++r) {
          const int row = m0 + wm + mt * 16 + qd * 4 + r;
          ((float*)Cv)[(size_t)z * cZ + (size_t)row * N + col] = acc[mt][nt][r];
        }
    }
  } else {  // MODE 1
#pragma unroll
    for (int nt = 0; nt < 4; ++nt) {
      const int col = n0 + wn + nt * 16 + ln;
      const float bc = bias[512 * z + col];
#pragma unroll
      for (int mt = 0; mt < 4; ++mt)
#pragma unroll
        for (int r = 0; r < 4; ++r) {
          const int row = m0 + wm + mt * 16 + qd * 4 + r;
          const int bidx = row >> 8, ml = row & 255;
          ((short*)Cv)[((size_t)(bidx * H_ + z) * M_ + ml) * N + col] = f2bf(acc[mt][nt][r] + bc);
        }
    }
  }
}

// ---------------------------------------------------------------------------
// 16 MFMAs of one 64x32 C-quadrant over K=64, setprio-wrapped (T5).
// ---------------------------------------------------------------------------
template<int MH, int NH>
static __device__ __forceinline__ void mfma_quad(
    f32x4 (&acc)[8][4], const bf16x8 (&a)[4][2], const bf16x8 (&bfr)[2][2])
{
  __builtin_amdgcn_s_setprio(1);
#pragma unroll
  for (int kk = 0; kk < 2; ++kk)
#pragma unroll
    for (int mt = 0; mt < 4; ++mt)
#pragma unroll
      for (int nt = 0; nt < 2; ++nt)
        acc[MH * 4 + mt][NH * 2 + nt] = __builtin_amdgcn_mfma_f32_16x16x32_bf16(
            a[mt][kk], bfr[nt][kk], acc[MH * 4 + mt][NH * 2 + nt], 0, 0, 0);
  __builtin_amdgcn_s_setprio(0);
}

// 8 MFMAs of one 64x16-per-lane... (128x16 C strip) over K=64 for pv128.
template<int MH, int NT>
static __device__ __forceinline__ void mfma_oct(
    f32x4 (&acc)[8][2], const bf16x8 (&a)[4][2], const bf16x8 (&bv)[2])
{
  __builtin_amdgcn_s_setprio(1);
#pragma unroll
  for (int kk = 0; kk < 2; ++kk)
#pragma unroll
    for (int mt = 0; mt < 4; ++mt)
      acc[MH * 4 + mt][NT] = __builtin_amdgcn_mfma_f32_16x16x32_bf16(
          a[mt][kk], bv[kk], acc[MH * 4 + mt][NT], 0, 0, 0);
  __builtin_amdgcn_s_setprio(0);
}

// ---------------------------------------------------------------------------
// QK kernel: 256x256 tile, BK=64, 4 phases/K-tile, 512 thr (8 waves 2Mx4N).
// Read order per tile: ph0 (0,0): A-mh0(8)+B-nh0(4); ph1 (0,1): B-nh1(4);
// ph2 (1,1): A-mh1(8); ph3 (1,0): B-nh0 re-read(4).  24+4 reads/tile.
// Region lifetimes: A halves last read ph2 -> stage A01(t+2)->buf p at ph3
// (ph3 reads B only, disjoint). B region last read ph3 -> stage B01(t+1)
// ->buf p^1 at ph0 (prev occupant's last read was t-1 ph3).
// Boundary s_waitcnt vmcnt(4): drains A01(t+1) [issued t-1 ph3, 4.5-phase
// gap] and B01(t+1) [issued t ph0, 3.5-phase gap]; leaves A01(t+2) inflight.
// LDS swizzle: 16B chunk c of row r stored at c^(r&7) via pre-swizzled
// global source (rule 21); fragment ds_read_b128 conflict-free (measured 0).
// Epilogue: exp + rowsum atomics, then repack the 256x256 bf16 tile through
// LDS (XOR-swizzled, <=2-way write conflicts) -> 16B coalesced row stores
// (16 dwordx4/thread vs 128 scalar shorts before; fixes 1.8x sector waste).
// ---------------------------------------------------------------------------
template<int NKT>
__global__ __launch_bounds__(512, 2) void qk256(
    const short* __restrict__ Abase, const short* __restrict__ Bbase,
    short* __restrict__ Eb, float* __restrict__ Ls)
{
  __shared__ short lds[65536];   // A: 2buf x [2half][128][64] | B same at +32768
  const int t = threadIdx.x;
  const int w = t >> 6, lane = t & 63, qd = lane >> 4, ln = lane & 15;
  const int wr = w >> 2, wc = w & 3;
  const int b = blockIdx.x;                       // XCD pin: flat id % 8 == b
  const int n0 = blockIdx.y * 256, m0 = blockIdx.z * 256;

  const short* A  = Abase + (size_t)b * (2048 * 512) + (size_t)m0 * 512;
  const short* Bp = Bbase + (size_t)b * (2048 * 512) + (size_t)n0 * 512;

  // staging source map: linear LDS slot s <- global(row=s>>3, chunk=(s&7)^(row&7))
  const int s0 = w * 64 + lane, s1 = s0 + 512;
  const int sr0 = s0 >> 3, sc0 = ((s0 & 7) ^ (sr0 & 7)) * 8;
  const int sr1 = s1 >> 3, sc1 = ((s1 & 7) ^ (sr1 & 7)) * 8;
  auto stage = [&](const short* g, short* lbase) {
    gll16(g + (size_t)sr0 * 512 + sc0, lbase + w * 512);
    gll16(g + (size_t)sr1 * 512 + sc1, lbase + 4096 + w * 512);
  };

  const int cq0 = ((qd    ) ^ (ln & 7)) * 8;
  const int cq1 = ((4 + qd) ^ (ln & 7)) * 8;
  const int brow = (wc & 1) * 64;

  f32x4 acc[8][4];
#pragma unroll
  for (int i = 0; i < 8; ++i)
#pragma unroll
    for (int j = 0; j < 4; ++j) acc[i][j] = (f32x4){0.f, 0.f, 0.f, 0.f};

  // ---- prologue: tile0 fully + A01(1); wait tile0, keep A01(1) in flight
  stage(A,                  &lds[0]);              // A0(0)
  stage(A + 128 * 512,      &lds[8192]);           // A1(0)
  stage(Bp,                 &lds[32768]);          // B0(0)
  stage(Bp + 128 * 512,     &lds[32768 + 8192]);   // B1(0)
  stage(A + 64,             &lds[16384]);          // A0(1) -> buf1
  stage(A + 128 * 512 + 64, &lds[16384 + 8192]);   // A1(1) -> buf1
  asm volatile("s_waitcnt vmcnt(4)" ::: "memory");
  __builtin_amdgcn_s_barrier();

#pragma unroll 1
  for (int kt = 0; kt < NKT; ++kt) {
    const int p = kt & 1;
    short* Ah = &lds[p * 16384 + wr * 8192];
    short* Bh = &lds[32768 + p * 16384 + (wc >> 1) * 8192];
    bf16x8 a[4][2], bfr[2][2];

    // ---- ph0: A-mh0 + B-nh0; stage B01(kt+1) -> buf p^1
#pragma unroll
    for (int mt = 0; mt < 4; ++mt) {
      a[mt][0] = *(const bf16x8*)&Ah[(mt * 16 + ln) * 64 + cq0];
      a[mt][1] = *(const bf16x8*)&Ah[(mt * 16 + ln) * 64 + cq1];
    }
#pragma unroll
    for (int nt = 0; nt < 2; ++nt) {
      bfr[nt][0] = *(const bf16x8*)&Bh[(brow + nt * 16 + ln) * 64 + cq0];
      bfr[nt][1] = *(const bf16x8*)&Bh[(brow + nt * 16 + ln) * 64 + cq1];
    }
    if (kt + 1 < NKT) {
      stage(Bp + (kt + 1) * 64,             &lds[32768 + (p ^ 1) * 16384]);
      stage(Bp + 128 * 512 + (kt + 1) * 64, &lds[32768 + (p ^ 1) * 16384 + 8192]);
    }
    RAW_BAR(); LGKM_SYNC();
    mfma_quad<0, 0>(acc, a, bfr);
    RAW_BAR();

    // ---- ph1: B-nh1
#pragma unroll
    for (int nt = 0; nt < 2; ++nt) {
      bfr[nt][0] = *(const bf16x8*)&Bh[(brow + 32 + nt * 16 + ln) * 64 + cq0];
      bfr[nt][1] = *(const bf16x8*)&Bh[(brow + 32 + nt * 16 + ln) * 64 + cq1];
    }
    RAW_BAR(); LGKM_SYNC();
    mfma_quad<0, 1>(acc, a, bfr);
    RAW_BAR();

    // ---- ph2: A-mh1
#pragma unroll
    for (int mt = 0; mt < 4; ++mt) {
      a[mt][0] = *(const bf16x8*)&Ah[4096 + (mt * 16 + ln) * 64 + cq0];
      a[mt][1] = *(const bf16x8*)&Ah[4096 + (mt * 16 + ln) * 64 + cq1];
    }
    RAW_BAR(); LGKM_SYNC();
    mfma_quad<1, 1>(acc, a, bfr);
    RAW_BAR();

    // ---- ph3: B-nh0 again; stage A01(kt+2) -> buf p; boundary vmcnt(4)
#pragma unroll
    for (int nt = 0; nt < 2; ++nt) {
      bfr[nt][0] = *(const bf16x8*)&Bh[(brow + nt * 16 + ln) * 64 + cq0];
      bfr[nt][1] = *(const bf16x8*)&Bh[(brow + nt * 16 + ln) * 64 + cq1];
    }
    if (kt + 2 < NKT) {
      stage(A + (kt + 2) * 64,             &lds[p * 16384]);
      stage(A + 128 * 512 + (kt + 2) * 64, &lds[p * 16384 + 8192]);
    }
    RAW_BAR(); LGKM_SYNC();
    mfma_quad<1, 0>(acc, a, bfr);
    if (kt + 2 < NKT) { asm volatile("s_waitcnt vmcnt(4)" ::: "memory"); }
    else              { asm volatile("s_waitcnt vmcnt(0)" ::: "memory"); }
    RAW_BAR();
  }

  // ---- epilogue: exp, rowsum atomics, LDS repack, coalesced stores
#pragma unroll
  for (int i = 0; i < 8; ++i)
#pragma unroll
    for (int j = 0; j < 4; ++j)
#pragma unroll
      for (int r = 0; r < 4; ++r)
        acc[i][j][r] = __expf(acc[i][j][r] * SCALE);
#pragma unroll
  for (int i = 0; i < 8; ++i)
#pragma unroll
    for (int r = 0; r < 4; ++r) {
      float rs = acc[i][0][r] + acc[i][1][r] + acc[i][2][r] + acc[i][3][r];
      rs += __shfl_xor(rs, 1);
      rs += __shfl_xor(rs, 2);
      rs += __shfl_xor(rs, 4);
      rs += __shfl_xor(rs, 8);
      if (ln == 0) {
        const int row = m0 + wr * 128 + i * 16 + qd * 4 + r;
        atomicAdd(&Ls[(size_t)b * 2048 + row], rs);
      }
    }
  // repack: lds[row*256 + (col ^ ((row&7)<<3))] (shorts), row/col local
#pragma unroll
  for (int i = 0; i < 8; ++i)
#pragma unroll
    for (int j = 0; j < 4; ++j)
#pragma unroll
      for (int r = 0; r < 4; ++r) {
        const int row = wr * 128 + i * 16 + qd * 4 + r;
        const int col = wc * 64 + j * 16 + ln;
        lds[row * 256 + (col ^ ((row & 7) << 3))] = f2bf(acc[i][j][r]);
      }
  LGKM_WAIT();
  RAW_BAR();
  short* Cb = Eb + (size_t)b * 2048 * 2048;
#pragma unroll
  for (int it = 0; it < 16; ++it) {
    const int flat = it * 512 + t;
    const int row = flat >> 5, c = flat & 31;
    bf16x8 v = *(const bf16x8*)&lds[row * 256 + ((c ^ (row & 7)) * 8)];
    *(bf16x8*)(Cb + (size_t)(m0 + row) * 2048 + n0 + c * 8) = v;
  }
}

// ---------------------------------------------------------------------------
// PV kernel: 256x128 tile, BK=64, K=2048 (NKT=32), 512 thr (8 waves 2Mx4N,
// wave tile 128x32), grid (8,4,8)=256 blocks -> full GPU (old MODE3 grid was
// 128 blocks = half the CUs idle). Same deep schedule as qk256:
// ph0 (0,0): A-mh0(8)+B-nt0(2), stage B(t+1)->p^1; ph1 (0,1): B-nt1(2);
// ph2 (1,1): A-mh1(8); ph3 (1,0): B-nt0 re(2), stage A01(t+2)->p;
// boundary vmcnt(4). LDS 96 KiB: A 2x16384 shorts, B 2x8192 shorts.
// Epilogue: normalize + eself*mv, repack 256x128 bf16 through LDS,
// 256B coalesced row stores into the concat layout.
// ---------------------------------------------------------------------------
template<int NKT>
__global__ __launch_bounds__(512, 2) void pv128(
    const short* __restrict__ Abase, const short* __restrict__ Bbase,
    short* __restrict__ valb, const float* __restrict__ Ls,
    const float* __restrict__ eselfp, const short* __restrict__ mvbp)
{
  __shared__ short lds[49152];
  const int t = threadIdx.x;
  const int w = t >> 6, lane = t & 63, qd = lane >> 4, ln = lane & 15;
  const int wr = w >> 2, wc = w & 3;
  const int b = blockIdx.x;                       // XCD pin
  const int n0 = blockIdx.y * 128;
  const int bz = blockIdx.z;                      // head tile: m0 = bz*256
  const int m0 = bz * 256;

  const short* A  = Abase + (size_t)b * (2048 * 2048) + (size_t)m0 * 2048;
  const short* Bp = Bbase + (size_t)b * (512 * 2048) + (size_t)n0 * 2048;

  const int s0 = w * 64 + lane, s1 = s0 + 512;
  const int sr0 = s0 >> 3, sc0 = ((s0 & 7) ^ (sr0 & 7)) * 8;
  const int sr1 = s1 >> 3, sc1 = ((s1 & 7) ^ (sr1 & 7)) * 8;
  auto stage = [&](const short* g, short* lbase) {
    gll16(g + (size_t)sr0 * 2048 + sc0, lbase + w * 512);
    gll16(g + (size_t)sr1 * 2048 + sc1, lbase + 4096 + w * 512);
  };

  const int cq0 = ((qd    ) ^ (ln & 7)) * 8;
  const int cq1 = ((4 + qd) ^ (ln & 7)) * 8;
  const int brow = wc * 32;

  f32x4 acc[8][2];
#pragma unroll
  for (int i = 0; i < 8; ++i)
#pragma unroll
    for (int j = 0; j < 2; ++j) acc[i][j] = (f32x4){0.f, 0.f, 0.f, 0.f};

  // ---- prologue: tile0 (A0,A1,B) + A01(1); wait tile0, keep A01(1)
  stage(A,                   &lds[0]);              // A0(0)
  stage(A + 128 * 2048,      &lds[8192]);           // A1(0)
  stage(Bp,                  &lds[32768]);          // B(0)
  stage(A + 64,              &lds[16384]);          // A0(1) -> buf1
  stage(A + 128 * 2048 + 64, &lds[16384 + 8192]);   // A1(1) -> buf1
  asm volatile("s_waitcnt vmcnt(4)" ::: "memory");
  __builtin_amdgcn_s_barrier();

#pragma unroll 1
  for (int kt = 0; kt < NKT; ++kt) {
    const int p = kt & 1;
    short* Ah = &lds[p * 16384 + wr * 8192];
    short* Bh = &lds[32768 + p * 8192];
    bf16x8 a[4][2], bv[2];

    // ---- ph0: A-mh0 + B-nt0; stage B(kt+1) -> buf p^1
#pragma unroll
    for (int mt = 0; mt < 4; ++mt) {
      a[mt][0] = *(const bf16x8*)&Ah[(mt * 16 + ln) * 64 + cq0];
      a[mt][1] = *(const bf16x8*)&Ah[(mt * 16 + ln) * 64 + cq1];
    }
    bv[0] = *(const bf16x8*)&Bh[(brow + ln) * 64 + cq0];
    bv[1] = *(const bf16x8*)&Bh[(brow + ln) * 64 + cq1];
    if (kt + 1 < NKT)
      stage(Bp + (kt + 1) * 64, &lds[32768 + (p ^ 1) * 8192]);
    RAW_BAR(); LGKM_SYNC();
    mfma_oct<0, 0>(acc, a, bv);
    RAW_BAR();

    // ---- ph1: B-nt1
    bv[0] = *(const bf16x8*)&Bh[(brow + 16 + ln) * 64 + cq0];
    bv[1] = *(const bf16x8*)&Bh[(brow + 16 + ln) * 64 + cq1];
    RAW_BAR(); LGKM_SYNC();
    mfma_oct<0, 1>(acc, a, bv);
    RAW_BAR();

    // ---- ph2: A-mh1
#pragma unroll
    for (int mt = 0; mt < 4; ++mt) {
      a[mt][0] = *(const bf16x8*)&Ah[4096 + (mt * 16 + ln) * 64 + cq0];
      a[mt][1] = *(const bf16x8*)&Ah[4096 + (mt * 16 + ln) * 64 + cq1];
    }
    RAW_BAR(); LGKM_SYNC();
    mfma_oct<1, 1>(acc, a, bv);
    RAW_BAR();

    // ---- ph3: B-nt0 again; stage A01(kt+2) -> buf p; boundary vmcnt(4)
    bv[0] = *(const bf16x8*)&Bh[(brow + ln) * 64 + cq0];
    bv[1] = *(const bf16x8*)&Bh[(brow + ln) * 64 + cq1];
    if (kt + 2 < NKT) {
      stage(A + (kt + 2) * 64,              &lds[p * 16384]);
      stage(A + 128 * 2048 + (kt + 2) * 64, &lds[p * 16384 + 8192]);
    }
    RAW_BAR(); LGKM_SYNC();
    mfma_oct<1, 0>(acc, a, bv);
    if (kt + 2 < NKT) { asm volatile("s_waitcnt vmcnt(4)" ::: "memory"); }
    else              { asm volatile("s_waitcnt vmcnt(0)" ::: "memory"); }
    RAW_BAR();
  }

  // ---- epilogue: normalize + self-attn term, LDS repack, coalesced stores
#pragma unroll
  for (int i = 0; i < 8; ++i)
#pragma unroll
    for (int r = 0; r < 4; ++r) {
      const int row = wr * 128 + i * 16 + qd * 4 + r;   // local row, R = m0+row
      const float es  = eselfp[(size_t)b * 2048 + m0 + row];
      const float inv = 1.f / (es + Ls[(size_t)b * 2048 + m0 + row]);
      const short* mvr = mvbp + ((size_t)(b * 256 + row)) * 512;
#pragma unroll
      for (int j = 0; j < 2; ++j) {
        const int lcol = wc * 32 + j * 16 + ln;
        const float v = (acc[i][j][r] + es * bf2f(mvr[n0 + lcol])) * inv;
        lds[row * 128 + (lcol ^ ((row & 7) << 3))] = f2bf(v);
      }
    }
  LGKM_WAIT();
  RAW_BAR();
  // out rows: valb[(b*256+row)*4096 + bz*512 + n0 + ...], 256B per row here
#pragma unroll
  for (int it = 0; it < 8; ++it) {
    const int flat = it * 512 + t;
    const int row = flat >> 4, c = flat & 15;
    bf16x8 v = *(const bf16x8*)&lds[row * 128 + ((c ^ (row & 7)) * 8)];
    *(bf16x8*)(valb + ((size_t)(b * 256 + row)) * 4096 + (size_t)bz * 512 + n0 + c * 8) = v;
  }
}

// ---------------------------------------------------------------------------
// merged K/V projection, BK=32, 2-barrier single-buffer (16 KB LDS).
// ---------------------------------------------------------------------------
template<bool TRANSV>
__global__ __launch_bounds__(256, 3) void proj_kv(
    const short* __restrict__ A,
    const short* __restrict__ WkT, const short* __restrict__ WvT,
    const float* __restrict__ bk, const float* __restrict__ bv,
    short* __restrict__ Ck, short* __restrict__ Cvv)
{
  __shared__ short Sh[8192];
  short* As  = Sh;
  short* Bks = Sh + 4096;
  short* Bvs = Sh + 6144;
  const int t = threadIdx.x;
  const int w = t >> 6, lane = t & 63, qd = lane >> 4, ln = lane & 15;
  const int n0 = blockIdx.x * 64, m0 = blockIdx.y * 128;
  const int wm = (w & 1) * 64, wn2 = (w >> 1) * 32;

  const int rr = t >> 2, g0 = t & 3;
  const int gs0 = g0 ^ ((rr >> 1) & 3);
  const int gs1 = g0 ^ (((rr + 64) >> 1) & 3);
  const short* ga0 = A + (size_t)(m0 + rr) * 512 + gs0 * 8;
  const short* ga1 = A + (size_t)(m0 + rr + 64) * 512 + gs1 * 8;
  const short* gbk = WkT + (size_t)(n0 + rr) * 512 + gs0 * 8;
  const short* gbv = WvT + (size_t)(n0 + rr) * 512 + gs0 * 8;

  int aoff[4], boff[2];
#pragma unroll
  for (int mt = 0; mt < 4; ++mt) {
    int r = wm + mt * 16 + ln;
    aoff[mt] = r * 32 + (qd ^ ((r >> 1) & 3)) * 8;
  }
#pragma unroll
  for (int nt = 0; nt < 2; ++nt) {
    int r = wn2 + nt * 16 + ln;
    boff[nt] = r * 32 + (qd ^ ((r >> 1) & 3)) * 8;
  }

  f32x4 accK[4][2], accV[4][2];
#pragma unroll
  for (int mt = 0; mt < 4; ++mt)
#pragma unroll
    for (int nt = 0; nt < 2; ++nt) {
      accK[mt][nt] = (f32x4){0.f, 0.f, 0.f, 0.f};
      accV[mt][nt] = (f32x4){0.f, 0.f, 0.f, 0.f};
    }

  for (int kc = 0; kc < 512; kc += 32) {
    __syncthreads();
    gll16(ga0 + kc, &As[w * 512]);
    gll16(ga1 + kc, &As[2048 + w * 512]);
    gll16(gbk + kc, &Bks[w * 512]);
    gll16(gbv + kc, &Bvs[w * 512]);
    __syncthreads();

    bf16x8 af[4], bkf[2], bvf[2];
#pragma unroll
    for (int mt = 0; mt < 4; ++mt) af[mt] = *(const bf16x8*)&As[aoff[mt]];
#pragma unroll
    for (int nt = 0; nt < 2; ++nt) {
      bkf[nt] = *(const bf16x8*)&Bks[boff[nt]];
      bvf[nt] = *(const bf16x8*)&Bvs[boff[nt]];
    }
#pragma unroll
    for (int mt = 0; mt < 4; ++mt)
#pragma unroll
      for (int nt = 0; nt < 2; ++nt) {
        accK[mt][nt] = __builtin_amdgcn_mfma_f32_16x16x32_bf16(af[mt], bkf[nt], accK[mt][nt], 0, 0, 0);
        accV[mt][nt] = __builtin_amdgcn_mfma_f32_16x16x32_bf16(af[mt], bvf[nt], accV[mt][nt], 0, 0, 0);
      }
  }

#pragma unroll
  for (int nt = 0; nt < 2; ++nt) {
    const int col = n0 + wn2 + nt * 16 + ln;
    const float bc = bk[col];
#pragma unroll
    for (int mt = 0; mt < 4; ++mt)
#pragma unroll
      for (int r = 0; r < 4; ++r) {
        const int row = m0 + wm + mt * 16 + qd * 4 + r;
        Ck[(size_t)row * 512 + col] = f2bf(accK[mt][nt][r] + bc);
      }
  }

  if constexpr (!TRANSV) {
#pragma unroll
    for (int nt = 0; nt < 2; ++nt) {
      const int col = n0 + wn2 + nt * 16 + ln;
      const float bc = bv[col];
#pragma unroll
      for (int mt = 0; mt < 4; ++mt)
#pragma unroll
        for (int r = 0; r < 4; ++r) {
          const int row = m0 + wm + mt * 16 + qd * 4 + r;
          Cvv[(size_t)row * 512 + col] = f2bf(accV[mt][nt][r] + bc);
        }
    }
  } else {
    __syncthreads();
    short* ep = &Sh[w * 1280];
    const int lr = lane >> 1, lc16 = (lane & 1) * 16;
#pragma unroll
    for (int pass = 0; pass < 2; ++pass) {
#pragma unroll
      for (int mh = 0; mh < 2; ++mh) {
        const int mt = pass * 2 + mh;
#pragma unroll
        for (int nt = 0; nt < 2; ++nt) {
          const float bc = bv[n0 + wn2 + nt * 16 + ln];
#pragma unroll
          for (int r = 0; r < 4; ++r)
            ep[(nt * 16 + ln) * 40 + mh * 16 + qd * 4 + r] = f2bf(accV[mt][nt][r] + bc);
        }
      }
      LGKM_WAIT();
      const int srow0 = m0 + wm + pass * 32;
      const int bidx = srow0 >> 11;
      const int sloc = (srow0 & 2047) + lc16;
      const int pcol = n0 + wn2 + lr;
      short* outp = Cvv + (size_t)bidx * P_ * S_ + (size_t)pcol * S_ + sloc;
      *(bf16x8*)outp = *(const bf16x8*)&ep[lr * 40 + lc16];
      *(bf16x8*)(outp + 8) = *(const bf16x8*)&ep[lr * 40 + lc16 + 8];
      LGKM_WAIT();
    }
  }
}

// ---------------------------------------------------------------------------
// split-K reduce for Wo: out = sum_z partial[z] + bo[col], fp32
// ---------------------------------------------------------------------------
__global__ __launch_bounds__(256) void reduce_wo(
    const float* __restrict__ partial, const float* __restrict__ bo,
    float* __restrict__ out)
{
  const int idx4 = blockIdx.x * 256 + threadIdx.x;
  float4 s = ((const float4*)bo)[idx4 & 127];
#pragma unroll
  for (int zz = 0; zz < 4; ++zz) {
    float4 p = ((const float4*)partial)[(size_t)zz * 262144 + idx4];
    s.x += p.x; s.y += p.y; s.z += p.z; s.w += p.w;
  }
  ((float4*)out)[idx4] = s;
}

// ---------------------------------------------------------------------------
// self-score + Ls zeroing
// ---------------------------------------------------------------------------
__global__ __launch_bounds__(256) void selfscore(
    const short* __restrict__ qb, const short* __restrict__ mkb,
    float* __restrict__ eself, float* __restrict__ Ls)
{
  const int z = blockIdx.x, t = threadIdx.x;
  const short* qr = qb + ((size_t)z * M_ + t) * P_;
  const short* mr = mkb + ((size_t)(z >> 3) * M_ + t) * P_;
  float s = 0.f;
#pragma unroll 8
  for (int c = 0; c < P_; c += 8) {
    bf16x8 qv = *(const bf16x8*)(qr + c);
    bf16x8 mv = *(const bf16x8*)(mr + c);
#pragma unroll
    for (int j = 0; j < 8; ++j) s += bf2f(qv[j]) * bf2f(mv[j]);
  }
  eself[(size_t)z * M_ + t] = __expf(s * SCALE);
  Ls[(size_t)z * M_ + t] = 0.f;
}

// ---------------------------------------------------------------------------
extern "C" void kernel_launch(void* const* d_in, const int* in_sizes, int n_in,
                              void* d_out, int out_size, void* d_ws, size_t ws_size,
                              hipStream_t stream) {
  const float* input_seq = (const float*)d_in[0];
  const float* memcells  = (const float*)d_in[1];
  const float* Wk = (const float*)d_in[2];
  const float* bk = (const float*)d_in[3];
  const float* Wv = (const float*)d_in[4];
  const float* bv = (const float*)d_in[5];
  const float* Wq = (const float*)d_in[6];
  const float* bq = (const float*)d_in[7];
  const float* Wo = (const float*)d_in[8];
  const float* bo = (const float*)d_in[9];
  float* out = (float*)d_out;

  short* ws = (short*)d_ws;
  size_t o = 0;
  short* valb = ws + o; o += (size_t)B_ * M_ * H_ * P_;      // 8388608
  short* WoT  = ws + o; o += (size_t)(H_ * P_) * P_;          // 2097152
  short* mvb  = ws + o; o += (size_t)B_ * M_ * P_;            // 1048576
  short* mkb  = ws + o; o += (size_t)B_ * M_ * P_;            // 1048576
  short* qb   = ws + o; o += (size_t)B_ * H_ * M_ * P_;       // 8388608
  short* ivT  = ws + o; o += (size_t)B_ * P_ * S_;            // 8388608
  short* ikb  = ws + o; o += (size_t)B_ * S_ * P_;            // 8388608
  float* partial = (float*)(ws + o); o += (size_t)B_ * H_ * M_ * P_;  // 16 MB
  float* eself = (float*)(ws + o); o += 2 * (size_t)B_ * H_ * M_;
  float* Ls    = (float*)(ws + o); o += 2 * (size_t)B_ * H_ * M_;
  short* region2 = ws + o;                                    // Eb region (64 MB)
  short* Ab  = region2;
  short* Mb  = Ab + (size_t)B_ * S_ * D_;
  short* WkT = Mb + (size_t)B_ * M_ * D_;
  short* WvT = WkT + (size_t)D_ * P_;
  short* WqT = WvT + (size_t)D_ * P_;
  short* Eb  = region2;   // overlaps the above (all dead before E is written)

  dim3 blk(256);

  const int n4A = B_ * S_ * D_ / 4;
  const int n4M = B_ * M_ * D_ / 4;
  cast_both<<<dim3((n4A + n4M) / 256), blk, 0, stream>>>(input_seq, Ab, n4A, memcells, Mb);
  wtrans_all<<<dim3(16, 16, 10), blk, 0, stream>>>(Wk, Wv, Wq, WkT, WvT, WqT);
  wtrans_wo<<<dim3(16, 128), blk, 0, stream>>>(Wo, WoT);

  proj_kv<true><<<dim3(8, 128), blk, 0, stream>>>(Ab, WkT, WvT, bk, bv, ikb, ivT);
  proj_kv<false><<<dim3(8, 16), blk, 0, stream>>>(Mb, WkT, WvT, bk, bv, mkb, mvb);

  // q projection: MODE 1, z = h
  gemm128<1, 512, 512, 512, 512><<<dim3(4, 16, 8), blk, 0, stream>>>(
      Mb, WqT, bq, qb, 0, (size_t)D_ * P_, 0, nullptr, nullptr, nullptr);

  // eself + zero Ls (before QK's atomics)
  selfscore<<<dim3(64), blk, 0, stream>>>(qb, mkb, eself, Ls);

  // E = exp(scale * q @ ik^T) + fused row-sum; per-batch 2048x2048, K=512
  qk256<8><<<dim3(8, 8, 8), dim3(512), 0, stream>>>(qb, ikb, Eb, Ls);

  // val = normalize(E @ iv + eself*mv), concat layout; per-batch 2048x512,
  // K=2048; BN=128 -> grid 256 blocks (full GPU)
  pv128<32><<<dim3(8, 4, 8), dim3(512), 0, stream>>>(Eb, ivT, valb, Ls, eself, mvb);

  // Wo: split-K=4 partials, then reduce+bias
  gemm128<5, 1024, 512, 4096, 4096><<<dim3(4, 16, 4), blk, 0, stream>>>(
      valb, WoT, nullptr, partial, 1024, 1024,
      (size_t)2048 * 512, nullptr, nullptr, nullptr);
  reduce_wo<<<dim3(1024), blk, 0, stream>>>(partial, bo, out);
}